// Round 9
// baseline (803.563 us; speedup 1.0000x reference)
//
#include <hip/hip_runtime.h>
#include <hip/hip_bf16.h>
#include <math.h>

// Problem constants (B=32, S=1024, D=512 from reference setup_inputs)
#define BB 32
#define SS 1024
#define DD 512
#define OUT_ELEMS 33554432ull   // B*S*2D (output); scores follow at this offset

typedef _Float16 half8 __attribute__((ext_vector_type(8)));
typedef _Float16 half4 __attribute__((ext_vector_type(4)));
typedef float floatx4 __attribute__((ext_vector_type(4)));

// ws layout (bytes): denom 128K | cinv 128K | ct16 32M ([b][d][s] f16 of RAW ctx)
#define WS_DENOM_OFF 0ull
#define WS_CINV_OFF  131072ull
#define WS_CT_OFF    262144ull
#define WS_NEED_T1   (262144ull + 33554432ull)   // 32.3 MiB

// length dtype defense (R4/R7 PASSED with this): int32-word [1]==0 iff int64.
__device__ __forceinline__ int load_len(const int* __restrict__ len, int b) {
  const bool is64 = (len[1] == 0);
  return is64 ? (int)((const long long*)len)[b] : len[b];
}

// ---------------------------------------------------------------------------
// K0: L2-normalize rows. ctx -> cinv; qry -> qn fp32 into d_out q-slot.
// ---------------------------------------------------------------------------
__global__ __launch_bounds__(256) void k_norm(const float* __restrict__ ctx,
                                              const float* __restrict__ qry,
                                              float* __restrict__ out,
                                              float* __restrict__ cinv) {
  const int wid = threadIdx.x >> 6, lane = threadIdx.x & 63;
  const int row = blockIdx.x * 4 + wid;            // 0 .. 2*B*S-1
  const bool isq = row >= BB * SS;
  const int r = isq ? row - BB * SS : row;
  const float4* s4 = (const float4*)((isq ? qry : ctx) + (size_t)r * DD);
  float4 e0 = s4[lane];
  float4 e1 = s4[lane + 64];
  float ss = e0.x*e0.x + e0.y*e0.y + e0.z*e0.z + e0.w*e0.w
           + e1.x*e1.x + e1.y*e1.y + e1.z*e1.z + e1.w*e1.w;
  #pragma unroll
  for (int m = 32; m; m >>= 1) ss += __shfl_xor(ss, m);
  const float inv = (ss > 0.0f) ? (1.0f / sqrtf(ss)) : 1.0f;
  if (isq) {
    float4 o0 = {e0.x*inv, e0.y*inv, e0.z*inv, e0.w*inv};
    float4 o1 = {e1.x*inv, e1.y*inv, e1.z*inv, e1.w*inv};
    float4* dst = (float4*)(out + (size_t)r * (2 * DD));
    dst[lane] = o0;
    dst[lane + 64] = o1;
  } else if (lane == 0) {
    cinv[r] = inv;
  }
}

// ---------------------------------------------------------------------------
// K-TR: raw ctx fp32 [b][s][d] -> ct16 f16 [b][d][s] (64x64 LDS transpose).
// ---------------------------------------------------------------------------
__global__ __launch_bounds__(256) void k_tr(const float* __restrict__ ctx,
                                            _Float16* __restrict__ ct) {
  __shared__ _Float16 tile[64][72];
  const int b = blockIdx.z, dx = blockIdx.y, sx = blockIdx.x;
  const int t = threadIdx.x;
  const int s0 = sx * 64, d0 = dx * 64;
  const int sr = t >> 4, sc = (t & 15) * 4;
  #pragma unroll
  for (int it = 0; it < 4; ++it) {
    const int s = sr + it * 16;
    float4 v = *(const float4*)(ctx + (size_t)(b * SS + s0 + s) * DD + d0 + sc);
    tile[sc + 0][s] = (_Float16)v.x;
    tile[sc + 1][s] = (_Float16)v.y;
    tile[sc + 2][s] = (_Float16)v.z;
    tile[sc + 3][s] = (_Float16)v.w;
  }
  __syncthreads();
  const int dr = t >> 2, seg = (t & 3) * 16;
  _Float16* orow = ct + ((size_t)b * DD + d0 + dr) * SS + s0 + seg;
  *(half8*)orow = *(const half8*)&tile[dr][seg];
  *(half8*)(orow + 8) = *(const half8*)&tile[dr][seg + 8];
}

// ---------------------------------------------------------------------------
// K1: LDS-FREE, BARRIER-FREE QK^T (fp32-direct operands; no big-ws need).
// A = qn fp32 from out (row stride 2D), B = ctx fp32 * cinv[row] (hoisted),
// both converted to f16 in registers. Per kt: 16 float4 loads + cvt + 16 MFMA.
// Epilogue: mask + sigmoid, write sig fp32 UNNORMALIZED to scores region,
// per-row denom atomics. BM=BN=128, 4 waves 2x2 of 64x64. Grid 2048.
// ---------------------------------------------------------------------------
__global__ __launch_bounds__(256) void k_qk_lf32(const float* __restrict__ ctx,
                                                 const float* __restrict__ outq,
                                                 const float* __restrict__ cinv,
                                                 const int* __restrict__ len,
                                                 float* __restrict__ sig,
                                                 float* __restrict__ denom) {
  const int b = blockIdx.z, bx = blockIdx.x, by = blockIdx.y;
  const int t = threadIdx.x, lane = t & 63, wid = t >> 6;
  const int wm = wid >> 1, wn = wid & 1;
  const int rr = lane & 15, g = lane >> 4;
  const int L = load_len(len, b);

  floatx4 acc[4][4] = {};
  const float* abase = outq + (size_t)(b * SS + by * 128 + wm * 64 + rr) * (2 * DD);
  const int brow0 = b * SS + bx * 128 + wn * 64 + rr;
  const float* bbase = ctx + (size_t)brow0 * DD;
  float civ[4];
  #pragma unroll
  for (int j = 0; j < 4; ++j) civ[j] = cinv[brow0 + j * 16];

  for (int kt = 0; kt < DD / 32; ++kt) {
    const int ka = kt * 32 + g * 8;
    half8 af[4], bf[4];
    #pragma unroll
    for (int i = 0; i < 4; ++i) {
      const float* ap = abase + (size_t)(i * 16) * (2 * DD) + ka;
      float4 v0 = *(const float4*)ap;
      float4 v1 = *(const float4*)(ap + 4);
      af[i] = (half8){(_Float16)v0.x, (_Float16)v0.y, (_Float16)v0.z, (_Float16)v0.w,
                      (_Float16)v1.x, (_Float16)v1.y, (_Float16)v1.z, (_Float16)v1.w};
    }
    #pragma unroll
    for (int j = 0; j < 4; ++j) {
      const float* bp = bbase + (size_t)(j * 16) * DD + ka;
      float4 v0 = *(const float4*)bp;
      float4 v1 = *(const float4*)(bp + 4);
      const float c = civ[j];
      bf[j] = (half8){(_Float16)(v0.x*c), (_Float16)(v0.y*c), (_Float16)(v0.z*c), (_Float16)(v0.w*c),
                      (_Float16)(v1.x*c), (_Float16)(v1.y*c), (_Float16)(v1.z*c), (_Float16)(v1.w*c)};
    }
    #pragma unroll
    for (int i = 0; i < 4; ++i)
      #pragma unroll
      for (int j = 0; j < 4; ++j)
        acc[i][j] = __builtin_amdgcn_mfma_f32_16x16x32_f16(af[i], bf[j], acc[i][j], 0, 0, 0);
  }

  const int rowbase = by * 128 + wm * 64, colbase = bx * 128 + wn * 64;
  #pragma unroll
  for (int i = 0; i < 4; ++i) {
    #pragma unroll
    for (int r = 0; r < 4; ++r) {
      const int row = rowbase + i * 16 + g * 4 + r;
      float* srow = sig + (size_t)(b * SS + row) * SS;
      float rsum = 0.0f;
      #pragma unroll
      for (int j = 0; j < 4; ++j) {
        const int col = colbase + j * 16 + rr;
        float v = 0.0f;
        if (col < L) v = 1.0f / (1.0f + __expf(-acc[i][j][r]));
        srow[col] = v;
        rsum += v;
      }
      rsum += __shfl_xor(rsum, 1);
      rsum += __shfl_xor(rsum, 2);
      rsum += __shfl_xor(rsum, 4);
      rsum += __shfl_xor(rsum, 8);
      if (rr == 0) atomicAdd(&denom[b * SS + row], rsum);
    }
  }
}

// ---------------------------------------------------------------------------
// K2: LDS-FREE PV, zero in-loop barriers.
// A = sig fp32 -> in-register hi/lo f16 (2-pass compensated = R7 numerics);
// B = ct16 [b][d][s] (contiguous in k=s). attended = ((hi+lo)@ctx)*rds.
// Scores normalization deferred to a post-loop epilogue: ONE __syncthreads()
// after the k-loop (all waves' raw-sig loads complete), then all 256 threads
// re-read the block's 128KB sig slab (L2-hot from the k-loop) * rds -> write
// back in place. Race-free: block owns its 32 rows; write-after-all-reads.
// BM=32, BN=512, 4 waves 1x4 of 32x128. Grid 1024. LDS = 128 B (rds only).
// ---------------------------------------------------------------------------
__global__ __launch_bounds__(256) void k_pv_lf(float* __restrict__ sig,
                                               const _Float16* __restrict__ ct,
                                               const float* __restrict__ denom,
                                               const int* __restrict__ len,
                                               float* __restrict__ out) {
  __shared__ float rds[32];
  const int b = blockIdx.y, bm = blockIdx.x;
  const int t = threadIdx.x, lane = t & 63, wn = t >> 6;
  const int rr = lane & 15, g = lane >> 4;
  const int L = load_len(len, b);

  if (t < 32) {
    const int row = bm * 32 + t;
    rds[t] = (row < L) ? (1.0f / fmaxf(denom[b * SS + row], 1.0f)) : 0.0f;
  }
  // no barrier here: rds is first consumed after the post-loop barrier

  floatx4 acc[2][8] = {};
  float* ab = sig + (size_t)(b * SS + bm * 32 + rr) * SS;
  const _Float16* bb = ct + ((size_t)b * DD + wn * 128 + rr) * SS;

  for (int kt = 0; kt < SS / 32; ++kt) {
    const int ka = kt * 32 + g * 8;
    half8 ah[2], al[2], bh[8];
    #pragma unroll
    for (int i = 0; i < 2; ++i) {
      const float* ap = ab + (size_t)(i * 16) * SS + ka;
      float4 v0 = *(const float4*)ap;
      float4 v1 = *(const float4*)(ap + 4);
      const float va[8] = {v0.x, v0.y, v0.z, v0.w, v1.x, v1.y, v1.z, v1.w};
      #pragma unroll
      for (int e = 0; e < 8; ++e) {
        const _Float16 hh = (_Float16)va[e];
        ah[i][e] = hh;
        al[i][e] = (_Float16)(va[e] - (float)hh);
      }
    }
    #pragma unroll
    for (int j = 0; j < 8; ++j)
      bh[j] = *(const half8*)(bb + (size_t)(j * 16) * SS + ka);
    #pragma unroll
    for (int j = 0; j < 8; ++j)
      #pragma unroll
      for (int i = 0; i < 2; ++i) {
        acc[i][j] = __builtin_amdgcn_mfma_f32_16x16x32_f16(ah[i], bh[j], acc[i][j], 0, 0, 0);
        acc[i][j] = __builtin_amdgcn_mfma_f32_16x16x32_f16(al[i], bh[j], acc[i][j], 0, 0, 0);
      }
  }

  __syncthreads();   // all waves' raw-sig reads are done; rds visible

  // epilogue 1: normalize the block's scores slab in place (32 rows x 1024)
  {
    float* base = sig + (size_t)(b * SS + bm * 32) * SS;
    #pragma unroll
    for (int f = 0; f < 32; ++f) {
      const int idx = f * 256 + t;          // 8192 float4 in the slab
      const int row = idx >> 8;             // 256 float4 per row
      const float rd = rds[row];
      float4* p = (float4*)base + idx;
      float4 v = *p;
      v.x *= rd; v.y *= rd; v.z *= rd; v.w *= rd;
      *p = v;
    }
  }

  // epilogue 2: attended write
  #pragma unroll
  for (int i = 0; i < 2; ++i) {
    #pragma unroll
    for (int r = 0; r < 4; ++r) {
      const int lrow = i * 16 + g * 4 + r;
      const int row = bm * 32 + lrow;
      const float rd = rds[lrow];
      float* orow = out + (size_t)(b * SS + row) * (2 * DD) + DD;
      #pragma unroll
      for (int j = 0; j < 8; ++j)
        orow[wn * 128 + j * 16 + rr] = acc[i][j][r] * rd;
    }
  }
}

// ---------------------------------------------------------------------------
// Tier-0 fallback PV: R7-validated LDS pipeline (sig fp32 in-place).
// ---------------------------------------------------------------------------
__global__ __launch_bounds__(512) void k_pv_r7(const float* __restrict__ ctx,
                                               float* __restrict__ sig,
                                               const float* __restrict__ denom,
                                               const int* __restrict__ len,
                                               float* __restrict__ out) {
  __shared__ _Float16 Sh[64][40], Sl[64][40];
  __shared__ _Float16 Ch[512][40];
  __shared__ float rds[64];
  const int b = blockIdx.y, bm = blockIdx.x;
  const int t = threadIdx.x, lane = t & 63, wid = t >> 6;
  const int wm = wid >> 2, wn = wid & 3;
  const int rr = lane & 15, g = lane >> 4;
  const int L = load_len(len, b);
  if (t < 64) {
    const int row = bm * 64 + t;
    const float dv = denom[b * SS + row];
    rds[t] = (row < L) ? (1.0f / fmaxf(dv, 1.0f)) : 0.0f;
  }
  __syncthreads();
  floatx4 acc[2][8] = {};
  float* sbase = sig + (size_t)(b * SS + bm * 64) * SS;
  const float* cbase = ctx + (size_t)b * SS * DD;
  const int sr = t >> 3, scg = t & 7;
  const int kg = t & 7, dg = t >> 3;
  for (int kt = 0; kt < SS / 32; ++kt) {
    const int k0 = kt * 32;
    {
      float* sp = sbase + (size_t)sr * SS + k0 + scg * 4;
      float4 v = *(const float4*)sp;
      const float rd = rds[sr];
      float4 nv = {v.x * rd, v.y * rd, v.z * rd, v.w * rd};
      *(float4*)sp = nv;
      _Float16 h0 = (_Float16)v.x, h1 = (_Float16)v.y, h2 = (_Float16)v.z, h3 = (_Float16)v.w;
      *(half4*)&Sh[sr][scg * 4] = (half4){h0, h1, h2, h3};
      *(half4*)&Sl[sr][scg * 4] = (half4){(_Float16)(v.x - (float)h0), (_Float16)(v.y - (float)h1),
                                          (_Float16)(v.z - (float)h2), (_Float16)(v.w - (float)h3)};
    }
    #pragma unroll
    for (int it = 0; it < 2; ++it) {
      const int db = it * 256 + dg * 4;
      const float* cp = cbase + (size_t)(k0 + kg * 4) * DD + db;
      float4 v0 = *(const float4*)(cp);
      float4 v1 = *(const float4*)(cp + DD);
      float4 v2 = *(const float4*)(cp + 2 * DD);
      float4 v3 = *(const float4*)(cp + 3 * DD);
      const float f0[4] = {v0.x, v0.y, v0.z, v0.w};
      const float f1[4] = {v1.x, v1.y, v1.z, v1.w};
      const float f2[4] = {v2.x, v2.y, v2.z, v2.w};
      const float f3[4] = {v3.x, v3.y, v3.z, v3.w};
      #pragma unroll
      for (int i = 0; i < 4; ++i) {
        *(half4*)&Ch[db + i][kg * 4] =
            (half4){(_Float16)f0[i], (_Float16)f1[i], (_Float16)f2[i], (_Float16)f3[i]};
      }
    }
    __syncthreads();
    half8 sh[2], sl[2];
    #pragma unroll
    for (int i = 0; i < 2; ++i) {
      sh[i] = *(const half8*)&Sh[wm * 32 + i * 16 + rr][g * 8];
      sl[i] = *(const half8*)&Sl[wm * 32 + i * 16 + rr][g * 8];
    }
    #pragma unroll
    for (int j = 0; j < 8; ++j) {
      half8 ch = *(const half8*)&Ch[wn * 128 + j * 16 + rr][g * 8];
      #pragma unroll
      for (int i = 0; i < 2; ++i) {
        acc[i][j] = __builtin_amdgcn_mfma_f32_16x16x32_f16(sh[i], ch, acc[i][j], 0, 0, 0);
        acc[i][j] = __builtin_amdgcn_mfma_f32_16x16x32_f16(sl[i], ch, acc[i][j], 0, 0, 0);
      }
    }
    __syncthreads();
  }
  #pragma unroll
  for (int i = 0; i < 2; ++i) {
    #pragma unroll
    for (int r = 0; r < 4; ++r) {
      const int lrow = wm * 32 + i * 16 + g * 4 + r;
      const int row = bm * 64 + lrow;
      const float rd = rds[lrow];
      float* orow = out + (size_t)(b * SS + row) * (2 * DD) + DD;
      #pragma unroll
      for (int j = 0; j < 8; ++j) {
        const int d = wn * 128 + j * 16 + rr;
        orow[d] = acc[i][j][r] * rd;
      }
    }
  }
}

// ---------------------------------------------------------------------------
extern "C" void kernel_launch(void* const* d_in, const int* in_sizes, int n_in,
                              void* d_out, int out_size, void* d_ws, size_t ws_size,
                              hipStream_t stream) {
  const float* ctx = (const float*)d_in[0];
  const float* qry = (const float*)d_in[1];
  const int* len = (const int*)d_in[2];
  float* out = (float*)d_out;
  float* sig = out + OUT_ELEMS;          // fp32 scores output region
  char* ws = (char*)d_ws;
  float* denom = (float*)(ws + WS_DENOM_OFF);
  float* cinv  = (float*)(ws + WS_CINV_OFF);
  _Float16* ct = (_Float16*)(ws + WS_CT_OFF);
  const int t1 = (ws_size >= WS_NEED_T1) ? 1 : 0;  // constant across calls

  hipMemsetAsync(denom, 0, BB * SS * sizeof(float), stream);
  k_norm<<<(2 * BB * SS) / 4, 256, 0, stream>>>(ctx, qry, out, cinv);
  if (t1) k_tr<<<dim3(SS / 64, DD / 64, BB), 256, 0, stream>>>(ctx, ct);
  k_qk_lf32<<<dim3(SS / 128, SS / 128, BB), 256, 0, stream>>>(ctx, out, cinv, len, sig, denom);
  if (t1)
    k_pv_lf<<<dim3(SS / 32, BB), 256, 0, stream>>>(sig, ct, denom, len, out);
  else
    k_pv_r7<<<dim3(SS / 64, BB), 512, 0, stream>>>(ctx, sig, denom, len, out);
}